// Round 6
// baseline (574.859 us; speedup 1.0000x reference)
//
#include <hip/hip_runtime.h>
#include <math.h>

// GraphWaveNet forward, MI355X. Round 6:
//  - diff: back to 128x128/BK=64 (32 MFMA per barrier) for Lt>=4 [R5's 64x128
//    halved MFMA-per-barrier and regressed]; 64x128 kept only for Lt<=3.
//  - tcn: R5 scalar-weight version (no LDS) unchanged.
// Layouts:
//   h    : [B=16, C=32, t=13, N=1024] fp32 (residual stream, in place)
//   gm   : [m=bc*Lt+tt][N] bf16 compact per layer (mixed gated output)
//   g12  : [b][n][256] bf16 ; adpT : [w][v] bf16
//   skipT: [b][n][s=256] bf16 ; y1 : [b][e=512][n] bf16 ; out [B,N,O] fp32

#define NBATCH 16
#define LLEN 13
#define NNODE 1024

typedef __attribute__((ext_vector_type(8))) short bf16x8;
typedef __attribute__((ext_vector_type(4))) float f32x4;

#define GLOAD16(gp, lp) __builtin_amdgcn_global_load_lds( \
    (const __attribute__((address_space(1))) void*)(gp), \
    (__attribute__((address_space(3))) void*)(lp), 16, 0, 0)

static __device__ inline short f2bf(float x) {
    union { float f; unsigned u; } v; v.f = x;
    unsigned r = v.u + 0x7FFFu + ((v.u >> 16) & 1u);
    return (short)(r >> 16);
}
static __device__ inline float bf2f(short x) {
    union { unsigned u; float f; } v; v.u = ((unsigned)(unsigned short)x) << 16;
    return v.f;
}

// ---------------- adjacency stats: per-row (v) max and 1/sum ----------------
__global__ void adp_stats(const float* __restrict__ emb, float* __restrict__ mx,
                          float* __restrict__ inv) {
    int v = blockIdx.x;
    int tid = threadIdx.x;
    __shared__ float red[256];
    float ev[10];
#pragma unroll
    for (int k = 0; k < 10; ++k) ev[k] = emb[v * 10 + k];
    float sc[4];
#pragma unroll
    for (int j = 0; j < 4; ++j) {
        int w = tid + j * 256;
        float s = 0.f;
#pragma unroll
        for (int k = 0; k < 10; ++k) s += ev[k] * emb[w * 10 + k];
        sc[j] = fmaxf(s, 0.f);
    }
    float m = fmaxf(fmaxf(sc[0], sc[1]), fmaxf(sc[2], sc[3]));
    red[tid] = m;
    __syncthreads();
    for (int s = 128; s > 0; s >>= 1) {
        if (tid < s) red[tid] = fmaxf(red[tid], red[tid + s]);
        __syncthreads();
    }
    m = red[0];
    __syncthreads();
    float sum = 0.f;
#pragma unroll
    for (int j = 0; j < 4; ++j) sum += __expf(sc[j] - m);
    red[tid] = sum;
    __syncthreads();
    for (int s = 128; s > 0; s >>= 1) {
        if (tid < s) red[tid] += red[tid + s];
        __syncthreads();
    }
    if (tid == 0) { mx[v] = m; inv[v] = 1.f / red[0]; }
}

// ---------------- adpT[w][v] = softmax_v(relu(E E^T))[v][w] bf16 ------------
__global__ void adpT_kernel(const float* __restrict__ emb, const float* __restrict__ mx,
                            const float* __restrict__ inv, short* __restrict__ adpT) {
    int w = blockIdx.x;
    int tid = threadIdx.x;
    __shared__ float ew[10];
    if (tid < 10) ew[tid] = emb[w * 10 + tid];
    __syncthreads();
#pragma unroll
    for (int j = 0; j < 4; ++j) {
        int v = tid + j * 256;
        float s = 0.f;
#pragma unroll
        for (int k = 0; k < 10; ++k) s += ew[k] * emb[v * 10 + k];
        s = fmaxf(s, 0.f);
        adpT[w * 1024 + v] = f2bf(__expf(s - mx[v]) * inv[v]);
    }
}

// ---------------- start 1x1 conv: x[B,L,N,2] -> h[B,R,t,N] fp32 -------------
__global__ void start_kernel(const float* __restrict__ x, const float* __restrict__ w,
                             const float* __restrict__ b, float* __restrict__ h) {
    int n = blockIdx.x * 256 + threadIdx.x;
    int t = blockIdx.y;
    int bb = blockIdx.z;
    float2 xv = *(const float2*)(x + (size_t)((bb * LLEN + t) * NNODE + n) * 2);
#pragma unroll
    for (int r = 0; r < 32; ++r) {
        h[((bb * 32 + r) * LLEN + t) * NNODE + n] = w[r * 2] * xv.x + w[r * 2 + 1] * xv.y + b[r];
    }
}

// ---------------- weight repack: W_cat/sb_cat (skip) + e1w bf16 -------------
__global__ void repack_kernel(const float* __restrict__ skip_w, const float* __restrict__ skip_b,
                              const float* __restrict__ e1w, short* __restrict__ wcat,
                              float* __restrict__ sbcat, short* __restrict__ e1wb) {
    int idx = blockIdx.x * 256 + threadIdx.x;
    if (idx < 65536) {
        int s = idx >> 8, k = idx & 255, i = k >> 5, c = k & 31;
        wcat[idx] = f2bf(skip_w[(i * 256 + s) * 32 + c]);
    } else {
        int j = idx - 65536;
        e1wb[j] = f2bf(e1w[j]);
    }
    if (idx < 256) {
        float s = 0.f;
#pragma unroll
        for (int i = 0; i < 8; ++i) s += skip_b[i * 256 + idx];
        sbcat[idx] = s;
    }
}

// ---------------- TCN conv + gating + gcn channel-mix -> gm bf16 -------------
// Weights read with wave-uniform indices -> scalar loads (SGPR), no LDS.
__global__ __launch_bounds__(128) void tcn_mix_kernel(
        const float* __restrict__ h, short* __restrict__ gm,
        short* __restrict__ g12,
        const float* __restrict__ w, const float* __restrict__ bias,
        const float* __restrict__ gcnw,
        int d, int t0, int Lt, int li) {
    int tid = threadIdx.x;
    int n = blockIdx.x * 128 + tid;
    int tt = blockIdx.y;
    int t = t0 + tt;
    int bb = blockIdx.z;
    const float* hb = h + (((size_t)(bb * 32 * LLEN + t)) << 10) + n;
    float hp[32], hc[32];
#pragma unroll
    for (int c = 0; c < 32; ++c) {
        hp[c] = hb[(c * LLEN - d) * 1024];
        hc[c] = hb[(c * LLEN) * 1024];
    }
    float gv[32];
#pragma unroll 2
    for (int o = 0; o < 32; ++o) {
        float a0 = bias[o], a1 = 0.f;
#pragma unroll
        for (int c = 0; c < 32; ++c) {
            a0 += w[(o * 32 + c) * 2] * hp[c];
            a1 += w[(o * 32 + c) * 2 + 1] * hc[c];
        }
        float a = fminf(fmaxf(a0 + a1, -25.f), 25.f);
        float e = __expf(-a);
        float e2 = e * e;
        gv[o] = (1.f - e2) / ((1.f + e2) * (1.f + e));  // tanh(a)*sigmoid(a)
    }
    if (t == 12) {
        short* gp = g12 + (((size_t)(bb << 10) + n) << 8) + li * 32;
#pragma unroll
        for (int c = 0; c < 32; ++c) gp[c] = f2bf(gv[c]);
    }
#pragma unroll 2
    for (int o = 0; o < 32; ++o) {
        float a = 0.f;
#pragma unroll
        for (int c = 0; c < 32; ++c) a += gcnw[o * 32 + c] * gv[c];
        gm[(((size_t)((bb * 32 + o) * Lt + tt)) << 10) + n] = f2bf(a);
    }
}

// ---------------- diffusion MFMA + fused gcn epilogue, 128x128 tile ----------
// BK=64, 4 waves (2x2 of 64x64), xor-swizzled LDS; 32 MFMA per barrier pair.
__global__ __launch_bounds__(256) void diff_fused_128(const short* __restrict__ gm,
                                                      const short* __restrict__ adpT,
                                                      float* __restrict__ h,
                                                      const float* __restrict__ gb,
                                                      const float* __restrict__ bng,
                                                      const float* __restrict__ bnb,
                                                      const float* __restrict__ bnm,
                                                      const float* __restrict__ bnv,
                                                      int t0, int Lt) {
    __shared__ __align__(16) short As[128 * 64];
    __shared__ __align__(16) short Bs[128 * 64];
    __shared__ float sgb[32], sinv[32], smean[32], sbeta[32];
    int tid = threadIdx.x;
    int wave = tid >> 6, lane = tid & 63;
    int n0 = blockIdx.x * 128;
    int m0 = blockIdx.y * 128;
    if (tid < 32) {
        sgb[tid] = gb[tid];
        sinv[tid] = bng[tid] * rsqrtf(bnv[tid] + 1e-5f);
        smean[tid] = bnm[tid];
        sbeta[tid] = bnb[tid];
    }

    const short* srcA[4]; const short* srcB[4];
    short* dstA[4]; short* dstB[4];
#pragma unroll
    for (int j = 0; j < 4; ++j) {
        int slot = j * 256 + wave * 64 + lane;
        int row = slot >> 3, p = slot & 7;
        int col = (p ^ ((row >> 1) & 7)) * 8;
        srcA[j] = gm + (((size_t)(m0 + row)) << 10) + col;
        srcB[j] = adpT + (((size_t)(n0 + row)) << 10) + col;
        dstA[j] = As + slot * 8;
        dstB[j] = Bs + slot * 8;
    }

    int wm = (wave & 1) * 64, wn = (wave >> 1) * 64;
    int quad = lane >> 4, lrow = lane & 15;
    const short* paw = As + (wm + lrow) * 64;
    const short* pbw = Bs + (wn + lrow) * 64;
    int off0 = ((quad) ^ ((lrow >> 1) & 7)) * 8;
    int off1 = ((4 + quad) ^ ((lrow >> 1) & 7)) * 8;

    f32x4 acc[4][4] = {};
    for (int kk = 0; kk < 1024; kk += 64) {
#pragma unroll
        for (int j = 0; j < 4; ++j) {
            GLOAD16(srcA[j] + kk, dstA[j]);
            GLOAD16(srcB[j] + kk, dstB[j]);
        }
        __syncthreads();
#pragma unroll
        for (int ks = 0; ks < 2; ++ks) {
            int off = ks ? off1 : off0;
            bf16x8 a[4], b[4];
#pragma unroll
            for (int i = 0; i < 4; ++i) {
                a[i] = *(const bf16x8*)(paw + i * 16 * 64 + off);
                b[i] = *(const bf16x8*)(pbw + i * 16 * 64 + off);
            }
#pragma unroll
            for (int mi = 0; mi < 4; ++mi)
#pragma unroll
                for (int ni = 0; ni < 4; ++ni)
                    acc[mi][ni] = __builtin_amdgcn_mfma_f32_16x16x32_bf16(a[mi], b[ni], acc[mi][ni], 0, 0, 0);
        }
        __syncthreads();
    }
#pragma unroll
    for (int mi = 0; mi < 4; ++mi) {
#pragma unroll
        for (int r = 0; r < 4; ++r) {
            int m = m0 + wm + mi * 16 + quad * 4 + r;
            unsigned bc = (unsigned)m / (unsigned)Lt;
            int tt = m - (int)bc * Lt;
            int c = bc & 31;
            float invv = sinv[c], meanv = smean[c], betav = sbeta[c], gbv = sgb[c];
            float* crow = h + (((size_t)(bc * LLEN + t0 + tt)) << 10) + n0 + wn + lrow;
#pragma unroll
            for (int ni = 0; ni < 4; ++ni) {
                float v = fmaxf(acc[mi][ni][r] + gbv, 0.f) + crow[ni * 16];
                crow[ni * 16] = (v - meanv) * invv + betav;
            }
        }
    }
}

// ---------------- diffusion MFMA, 64x128 tile (small-Lt layers only) ---------
__global__ __launch_bounds__(256) void diff_fused_64(const short* __restrict__ gm,
                                                     const short* __restrict__ adpT,
                                                     float* __restrict__ h,
                                                     const float* __restrict__ gb,
                                                     const float* __restrict__ bng,
                                                     const float* __restrict__ bnb,
                                                     const float* __restrict__ bnm,
                                                     const float* __restrict__ bnv,
                                                     int t0, int Lt) {
    __shared__ __align__(16) short As[64 * 64];
    __shared__ __align__(16) short Bs[128 * 64];
    __shared__ float sgb[32], sinv[32], smean[32], sbeta[32];
    int tid = threadIdx.x;
    int wave = tid >> 6, lane = tid & 63;
    int n0 = blockIdx.x * 128;
    int m0 = blockIdx.y * 64;
    if (tid < 32) {
        sgb[tid] = gb[tid];
        sinv[tid] = bng[tid] * rsqrtf(bnv[tid] + 1e-5f);
        smean[tid] = bnm[tid];
        sbeta[tid] = bnb[tid];
    }

    const short* srcA[2]; short* dstA[2];
    const short* srcB[4]; short* dstB[4];
#pragma unroll
    for (int j = 0; j < 2; ++j) {
        int slot = j * 256 + wave * 64 + lane;
        int row = slot >> 3, p = slot & 7;
        int col = (p ^ ((row >> 1) & 7)) * 8;
        srcA[j] = gm + (((size_t)(m0 + row)) << 10) + col;
        dstA[j] = As + slot * 8;
    }
#pragma unroll
    for (int j = 0; j < 4; ++j) {
        int slot = j * 256 + wave * 64 + lane;
        int row = slot >> 3, p = slot & 7;
        int col = (p ^ ((row >> 1) & 7)) * 8;
        srcB[j] = adpT + (((size_t)(n0 + row)) << 10) + col;
        dstB[j] = Bs + slot * 8;
    }

    int wm = (wave & 1) * 32, wn = (wave >> 1) * 64;
    int quad = lane >> 4, lrow = lane & 15;
    const short* paw = As + (wm + lrow) * 64;
    const short* pbw = Bs + (wn + lrow) * 64;
    int off0 = ((quad) ^ ((lrow >> 1) & 7)) * 8;
    int off1 = ((4 + quad) ^ ((lrow >> 1) & 7)) * 8;

    f32x4 acc[2][4] = {};
    for (int kk = 0; kk < 1024; kk += 64) {
#pragma unroll
        for (int j = 0; j < 2; ++j) GLOAD16(srcA[j] + kk, dstA[j]);
#pragma unroll
        for (int j = 0; j < 4; ++j) GLOAD16(srcB[j] + kk, dstB[j]);
        __syncthreads();
#pragma unroll
        for (int ks = 0; ks < 2; ++ks) {
            int off = ks ? off1 : off0;
            bf16x8 a[2], b[4];
#pragma unroll
            for (int i = 0; i < 2; ++i) a[i] = *(const bf16x8*)(paw + i * 16 * 64 + off);
#pragma unroll
            for (int i = 0; i < 4; ++i) b[i] = *(const bf16x8*)(pbw + i * 16 * 64 + off);
#pragma unroll
            for (int mi = 0; mi < 2; ++mi)
#pragma unroll
                for (int ni = 0; ni < 4; ++ni)
                    acc[mi][ni] = __builtin_amdgcn_mfma_f32_16x16x32_bf16(a[mi], b[ni], acc[mi][ni], 0, 0, 0);
        }
        __syncthreads();
    }
#pragma unroll
    for (int mi = 0; mi < 2; ++mi) {
#pragma unroll
        for (int r = 0; r < 4; ++r) {
            int m = m0 + wm + mi * 16 + quad * 4 + r;
            unsigned bc = (unsigned)m / (unsigned)Lt;
            int tt = m - (int)bc * Lt;
            int c = bc & 31;
            float invv = sinv[c], meanv = smean[c], betav = sbeta[c], gbv = sgb[c];
            float* crow = h + (((size_t)(bc * LLEN + t0 + tt)) << 10) + n0 + wn + lrow;
#pragma unroll
            for (int ni = 0; ni < 4; ++ni) {
                float v = fmaxf(acc[mi][ni][r] + gbv, 0.f) + crow[ni * 16];
                crow[ni * 16] = (v - meanv) * invv + betav;
            }
        }
    }
}

// ---------------- skip GEMM: skipT[b][n][s] = relu(Wcat @ g12 + sbcat) bf16 --
__global__ __launch_bounds__(256) void skip_mfma(const short* __restrict__ g12,
                                                 const short* __restrict__ wcat,
                                                 const float* __restrict__ sbcat,
                                                 short* __restrict__ skipT) {
    __shared__ __align__(16) short As[128 * 64];
    __shared__ __align__(16) short Bs[128 * 64];
    int tid = threadIdx.x;
    int wave = tid >> 6, lane = tid & 63;
    int s0 = blockIdx.x * 128;
    int m0 = blockIdx.y * 128;   // n rows
    int b = blockIdx.z;

    const short* srcA[4]; const short* srcB[4];
    short* dstA[4]; short* dstB[4];
#pragma unroll
    for (int j = 0; j < 4; ++j) {
        int slot = j * 256 + wave * 64 + lane;
        int row = slot >> 3, p = slot & 7;
        int col = (p ^ ((row >> 1) & 7)) * 8;
        srcA[j] = g12 + (((size_t)((b << 10) + m0 + row)) << 8) + col;
        srcB[j] = wcat + (((size_t)(s0 + row)) << 8) + col;
        dstA[j] = As + (j * 256 + wave * 64) * 8;
        dstB[j] = Bs + (j * 256 + wave * 64) * 8;
    }

    int wm = (wave & 1) * 64, wn = (wave >> 1) * 64;
    int quad = lane >> 4, lrow = lane & 15;
    const short* paw = As + (wm + lrow) * 64;
    const short* pbw = Bs + (wn + lrow) * 64;
    int off0 = ((quad) ^ ((lrow >> 1) & 7)) * 8;
    int off1 = ((4 + quad) ^ ((lrow >> 1) & 7)) * 8;

    f32x4 acc[4][4] = {};
    for (int kk = 0; kk < 256; kk += 64) {
#pragma unroll
        for (int j = 0; j < 4; ++j) {
            GLOAD16(srcA[j] + kk, dstA[j]);
            GLOAD16(srcB[j] + kk, dstB[j]);
        }
        __syncthreads();
#pragma unroll
        for (int ks = 0; ks < 2; ++ks) {
            int off = ks ? off1 : off0;
            bf16x8 a[4], b[4];
#pragma unroll
            for (int i = 0; i < 4; ++i) {
                a[i] = *(const bf16x8*)(paw + i * 16 * 64 + off);
                b[i] = *(const bf16x8*)(pbw + i * 16 * 64 + off);
            }
#pragma unroll
            for (int mi = 0; mi < 4; ++mi)
#pragma unroll
                for (int ni = 0; ni < 4; ++ni)
                    acc[mi][ni] = __builtin_amdgcn_mfma_f32_16x16x32_bf16(a[mi], b[ni], acc[mi][ni], 0, 0, 0);
        }
        __syncthreads();
    }
#pragma unroll
    for (int mi = 0; mi < 4; ++mi) {
#pragma unroll
        for (int r = 0; r < 4; ++r) {
            int m = m0 + wm + mi * 16 + quad * 4 + r;   // n
            short* crow = skipT + (((size_t)((b << 10) + m)) << 8) + s0 + wn + lrow;
#pragma unroll
            for (int ni = 0; ni < 4; ++ni) {
                int col = s0 + wn + lrow + ni * 16;
                crow[ni * 16] = f2bf(fmaxf(acc[mi][ni][r] + sbcat[col], 0.f));
            }
        }
    }
}

// ---------------- end1 MFMA: y1[b][e][n] = relu(e1w @ skipT + e1b) bf16 ------
__global__ __launch_bounds__(256) void end1_mfma(const short* __restrict__ skipT,
                                                 const short* __restrict__ e1wb,
                                                 const float* __restrict__ e1b,
                                                 short* __restrict__ y1) {
    __shared__ __align__(16) short As[128 * 64];
    __shared__ __align__(16) short Bs[128 * 64];
    int tid = threadIdx.x;
    int wave = tid >> 6, lane = tid & 63;
    int n0 = blockIdx.x * 128;
    int m0 = blockIdx.y * 128;   // e rows
    int b = blockIdx.z;

    const short* srcA[4]; const short* srcB[4];
    short* dstA[4]; short* dstB[4];
#pragma unroll
    for (int j = 0; j < 4; ++j) {
        int slot = j * 256 + wave * 64 + lane;
        int row = slot >> 3, p = slot & 7;
        int col = (p ^ ((row >> 1) & 7)) * 8;
        srcA[j] = e1wb + (((size_t)(m0 + row)) << 8) + col;
        srcB[j] = skipT + (((size_t)((b << 10) + n0 + row)) << 8) + col;
        dstA[j] = As + (j * 256 + wave * 64) * 8;
        dstB[j] = Bs + (j * 256 + wave * 64) * 8;
    }

    int wm = (wave & 1) * 64, wn = (wave >> 1) * 64;
    int quad = lane >> 4, lrow = lane & 15;
    const short* paw = As + (wm + lrow) * 64;
    const short* pbw = Bs + (wn + lrow) * 64;
    int off0 = ((quad) ^ ((lrow >> 1) & 7)) * 8;
    int off1 = ((4 + quad) ^ ((lrow >> 1) & 7)) * 8;

    f32x4 acc[4][4] = {};
    for (int kk = 0; kk < 256; kk += 64) {
#pragma unroll
        for (int j = 0; j < 4; ++j) {
            GLOAD16(srcA[j] + kk, dstA[j]);
            GLOAD16(srcB[j] + kk, dstB[j]);
        }
        __syncthreads();
#pragma unroll
        for (int ks = 0; ks < 2; ++ks) {
            int off = ks ? off1 : off0;
            bf16x8 a[4], b[4];
#pragma unroll
            for (int i = 0; i < 4; ++i) {
                a[i] = *(const bf16x8*)(paw + i * 16 * 64 + off);
                b[i] = *(const bf16x8*)(pbw + i * 16 * 64 + off);
            }
#pragma unroll
            for (int mi = 0; mi < 4; ++mi)
#pragma unroll
                for (int ni = 0; ni < 4; ++ni)
                    acc[mi][ni] = __builtin_amdgcn_mfma_f32_16x16x32_bf16(a[mi], b[ni], acc[mi][ni], 0, 0, 0);
        }
        __syncthreads();
    }
#pragma unroll
    for (int mi = 0; mi < 4; ++mi) {
#pragma unroll
        for (int r = 0; r < 4; ++r) {
            int e = m0 + wm + mi * 16 + quad * 4 + r;
            float bias = e1b[e];
            short* crow = y1 + (((size_t)(b * 512 + e)) << 10) + n0 + wn + lrow;
#pragma unroll
            for (int ni = 0; ni < 4; ++ni)
                crow[ni * 16] = f2bf(fmaxf(acc[mi][ni][r] + bias, 0.f));
        }
    }
}

// ---------------- end2: out[b,n,o] = W2 @ y1 + b2 (parallel e-split) --------
__global__ __launch_bounds__(256) void end2_kernel(const short* __restrict__ y1,
                                                   const float* __restrict__ w2,
                                                   const float* __restrict__ b2,
                                                   float* __restrict__ out) {
    __shared__ float sw[12][512];
    __shared__ float ps[4][12][128];
    int tid = threadIdx.x;
    for (int idx = tid; idx < 6144; idx += 256) sw[idx >> 9][idx & 511] = w2[idx];
    __syncthreads();
    int n0 = blockIdx.x * 128;
    int bb = blockIdx.y;
    int nl = (tid & 63) * 2;
    int ec = tid >> 6;
    float acc0[12], acc1[12];
#pragma unroll
    for (int o = 0; o < 12; ++o) { acc0[o] = 0.f; acc1[o] = 0.f; }
    const short* yb = y1 + (((size_t)(bb * 512 + ec * 128)) << 10) + n0 + nl;
    for (int e = 0; e < 128; ++e) {
        ushort2 yv = *(const ushort2*)(yb + ((size_t)e << 10));
        float v0 = bf2f((short)yv.x), v1 = bf2f((short)yv.y);
        const float* we = &sw[0][ec * 128 + e];
#pragma unroll
        for (int o = 0; o < 12; ++o) {
            float wv = we[o * 512];
            acc0[o] += wv * v0;
            acc1[o] += wv * v1;
        }
    }
#pragma unroll
    for (int o = 0; o < 12; ++o) {
        ps[ec][o][nl] = acc0[o];
        ps[ec][o][nl + 1] = acc1[o];
    }
    __syncthreads();
    for (int idx = tid; idx < 1536; idx += 256) {
        int o = idx >> 7, nn = idx & 127;
        float s = b2[o] + ps[0][o][nn] + ps[1][o][nn] + ps[2][o][nn] + ps[3][o][nn];
        out[((size_t)(bb * NNODE + n0 + nn)) * 12 + o] = s;
    }
}

extern "C" void kernel_launch(void* const* d_in, const int* in_sizes, int n_in,
                              void* d_out, int out_size, void* d_ws, size_t ws_size,
                              hipStream_t stream) {
    const float* x       = (const float*)d_in[0];
    const float* emb     = (const float*)d_in[1];
    const float* start_w = (const float*)d_in[2];
    const float* start_b = (const float*)d_in[3];
    const float* tcn_w   = (const float*)d_in[4];
    const float* tcn_b   = (const float*)d_in[5];
    const float* skip_w  = (const float*)d_in[6];
    const float* skip_b  = (const float*)d_in[7];
    const float* gcn_w   = (const float*)d_in[8];
    const float* gcn_b   = (const float*)d_in[9];
    const float* bn_g    = (const float*)d_in[10];
    const float* bn_b    = (const float*)d_in[11];
    const float* bn_m    = (const float*)d_in[12];
    const float* bn_v    = (const float*)d_in[13];
    const float* e1w     = (const float*)d_in[14];
    const float* e1b     = (const float*)d_in[15];
    const float* e2w     = (const float*)d_in[16];
    const float* e2b     = (const float*)d_in[17];
    float* out = (float*)d_out;

    char* wsb = (char*)d_ws;
    short* adpT  = (short*)(wsb);                    // 2,097,152
    float* mx    = (float*)(wsb + 2097152u);         // 4,096
    float* inv   = (float*)(wsb + 2101248u);         // 4,096
    float* h     = (float*)(wsb + 2105344u);         // 27,262,976
    short* gm    = (short*)(wsb + 29368320u);        // 12,582,912 (max Lt=12)
    short* g12   = (short*)(wsb + 41951232u);        // 8,388,608
    short* wcat  = (short*)(wsb + 50339840u);        // 131,072
    float* sbcat = (float*)(wsb + 50470912u);        // 1,024
    short* e1wb  = (short*)(wsb + 50471936u);        // 262,144
    short* skipT = (short*)(wsb + 50734080u);        // 8,388,608
    short* y1    = (short*)(wsb + 59122688u);        // 16,777,216

    adp_stats<<<dim3(1024), dim3(256), 0, stream>>>(emb, mx, inv);
    adpT_kernel<<<dim3(1024), dim3(256), 0, stream>>>(emb, mx, inv, adpT);
    start_kernel<<<dim3(4, 13, 16), dim3(256), 0, stream>>>(x, start_w, start_b, h);
    repack_kernel<<<dim3(768), dim3(256), 0, stream>>>(skip_w, skip_b, e1w, wcat, sbcat, e1wb);

    const int dil[8] = {1, 2, 1, 2, 1, 2, 1, 2};
    const int t0s[8] = {1, 3, 4, 6, 7, 9, 10, 12};
    for (int i = 0; i < 8; ++i) {
        int d = dil[i];
        int t0 = t0s[i];
        int Lt = 13 - t0;
        tcn_mix_kernel<<<dim3(8, Lt, 16), dim3(128), 0, stream>>>(
            h, gm, g12, tcn_w + i * 2048, tcn_b + i * 32, gcn_w + i * 1024,
            d, t0, Lt, i);
        if (Lt >= 4) {
            diff_fused_128<<<dim3(8, 4 * Lt), dim3(256), 0, stream>>>(
                gm, adpT, h, gcn_b + i * 32,
                bn_g + i * 32, bn_b + i * 32, bn_m + i * 32, bn_v + i * 32, t0, Lt);
        } else {
            diff_fused_64<<<dim3(8, 8 * Lt), dim3(256), 0, stream>>>(
                gm, adpT, h, gcn_b + i * 32,
                bn_g + i * 32, bn_b + i * 32, bn_m + i * 32, bn_v + i * 32, t0, Lt);
        }
    }

    skip_mfma<<<dim3(2, 8, 16), dim3(256), 0, stream>>>(g12, wcat, sbcat, skipT);
    end1_mfma<<<dim3(8, 4, 16), dim3(256), 0, stream>>>(skipT, e1wb, e1b, y1);
    end2_kernel<<<dim3(8, 16), dim3(256), 0, stream>>>(y1, e2w, e2b, out);
}